// Round 5
// baseline (1213.302 us; speedup 1.0000x reference)
//
#include <hip/hip_runtime.h>

typedef unsigned short ushort_t;

#define NN 10000
#define BB 8
#define TT 12
#define FF 8
#define HH 64
#define GG 192   // 3H
#define HORZ 12
#define EE 320000
#define MM (BB*NN) // 80000

// ---- ws layout (float words) ----
#define OFF_H    0u
#define OFF_F1   5120000u
#define OFF_F2   10240000u
#define OFF_B1   15360000u
#define OFF_B2   20480000u
#define OFF_BIAS 25600000u
#define OFF_W1   27520000u
#define OFF_DEGF 27521536u
#define OFF_DEGB 27531536u
#define OFF_CNTF 27541536u
#define OFF_CNTB 27551536u
#define OFF_PTRF 27561536u
#define OFF_PTRB 27571537u
#define OFF_EPKF 27581538u   // packed (idx, w) int2 per edge, fwd (640000 words)
#define OFF_EPKB 28221538u   // packed (idx, w) int2 per edge, bwd (640000 words)
#define OFF_FLAG 28861538u

typedef __attribute__((ext_vector_type(8))) short short8;
typedef __attribute__((ext_vector_type(4))) float f4v;

union I4S8 { int4 i; short8 s; };

__device__ __forceinline__ f4v mfma16(int4 a, int4 b, f4v c) {
    I4S8 ua, ub; ua.i = a; ub.i = b;
    return __builtin_amdgcn_mfma_f32_16x16x32_bf16(ua.s, ub.s, c, 0, 0, 0);
}

__device__ __forceinline__ unsigned f2bf_u(float f) {
    union { float f; unsigned u; } v; v.f = f;
    unsigned x = v.u;
    x += 0x7FFFu + ((x >> 16) & 1u);
    return x >> 16;
}
// split 8 fp32 into bf16 hi + bf16 lo fragments (packed)
__device__ __forceinline__ void hilo8(const float* f, int4& hi, int4& lo) {
    unsigned hb[8], lb[8];
    #pragma unroll
    for (int i = 0; i < 8; i++) {
        float v = f[i];
        unsigned h = f2bf_u(v);
        union { unsigned u; float fl; } bk; bk.u = h << 16;
        lb[i] = f2bf_u(v - bk.fl);
        hb[i] = h;
    }
    hi = make_int4((int)(hb[0]|(hb[1]<<16)), (int)(hb[2]|(hb[3]<<16)),
                   (int)(hb[4]|(hb[5]<<16)), (int)(hb[6]|(hb[7]<<16)));
    lo = make_int4((int)(lb[0]|(lb[1]<<16)), (int)(lb[2]|(lb[3]<<16)),
                   (int)(lb[4]|(lb[5]<<16)), (int)(lb[6]|(lb[7]<<16)));
}
// pack 8 fp32 -> bf16 (round-to-nearest) fragment
__device__ __forceinline__ int4 hi8(const float* f) {
    unsigned hb[8];
    #pragma unroll
    for (int i = 0; i < 8; i++) hb[i] = f2bf_u(f[i]);
    return make_int4((int)(hb[0]|(hb[1]<<16)), (int)(hb[2]|(hb[3]<<16)),
                     (int)(hb[4]|(hb[5]<<16)), (int)(hb[6]|(hb[7]<<16)));
}

__device__ __forceinline__ float f4c(const float4& v, int kk) {
    switch (kk) { case 0: return v.x; case 1: return v.y; case 2: return v.z; default: return v.w; }
}
#define FMA4(ACC, W, S) \
    ACC[0] = fmaf(S, W.x, ACC[0]); \
    ACC[1] = fmaf(S, W.y, ACC[1]); \
    ACC[2] = fmaf(S, W.z, ACC[2]); \
    ACC[3] = fmaf(S, W.w, ACC[3]);

// ---------------- utility ----------------
__global__ void zero_k(float* p, int n) {
    int i = blockIdx.x * 256 + threadIdx.x;
    if (i < n) p[i] = 0.f;
}

__global__ void flag_k(const int* __restrict__ ei, int* flag) {
    if (threadIdx.x == 0 && blockIdx.x == 0) {
        int o = ei[1] | ei[3] | ei[5] | ei[7] | ei[9] | ei[11] | ei[13];
        flag[0] = (o == 0) ? 1 : 0;
    }
}

__device__ __forceinline__ void load_edge(const int* __restrict__ ei, int isI64,
                                          int e, int& s, int& t) {
    if (isI64) {
        const long long* p = (const long long*)ei;
        s = (int)p[e]; t = (int)p[EE + e];
    } else {
        s = ei[e]; t = ei[EE + e];
    }
}

// ---------------- CSR build ----------------
__global__ void csr_count_k(const int* __restrict__ ei, const float* __restrict__ ew,
                            const int* __restrict__ flag,
                            int* cnt_f, int* cnt_b, float* deg_f, float* deg_b) {
    int e = blockIdx.x * 256 + threadIdx.x;
    if (e >= EE) return;
    int isI64 = flag[0];
    int s, t; load_edge(ei, isI64, e, s, t);
    if ((unsigned)s >= NN || (unsigned)t >= NN) return;
    float w = ew[e];
    atomicAdd(&cnt_f[t], 1); atomicAdd(&deg_f[t], w);
    atomicAdd(&cnt_b[s], 1); atomicAdd(&deg_b[s], w);
}

__global__ void scan_k(int* cnt_f, int* cnt_b, int* ptr_f, int* ptr_b) {
    int* cnt = blockIdx.x ? cnt_b : cnt_f;
    int* ptr = blockIdx.x ? ptr_b : ptr_f;
    __shared__ int part[256];
    int tid = threadIdx.x;
    const int CH = (NN + 255) / 256;
    int lo = tid * CH, hi = lo + CH; if (hi > NN) hi = NN; if (lo > NN) lo = NN;
    int s = 0;
    for (int i = lo; i < hi; i++) s += cnt[i];
    part[tid] = s;
    __syncthreads();
    if (tid == 0) {
        int run = 0;
        for (int i = 0; i < 256; i++) { int v = part[i]; part[i] = run; run += v; }
        ptr[NN] = run;
    }
    __syncthreads();
    int run = part[tid];
    for (int i = lo; i < hi; i++) { ptr[i] = run; run += cnt[i]; cnt[i] = 0; }
}

__global__ void csr_fill_k(const int* __restrict__ ei, const float* __restrict__ ew,
                           const int* __restrict__ flag,
                           const float* __restrict__ deg_f, const float* __restrict__ deg_b,
                           const int* __restrict__ ptr_f, const int* __restrict__ ptr_b,
                           int* cnt_f, int* cnt_b,
                           int* epk_f, int* epk_b) {
    int e = blockIdx.x * 256 + threadIdx.x;
    if (e >= EE) return;
    int isI64 = flag[0];
    int s, t; load_edge(ei, isI64, e, s, t);
    if ((unsigned)s >= NN || (unsigned)t >= NN) return;
    float w = ew[e];
    float df = deg_f[t];
    float nwf = w / ((df == 0.f) ? 1.f : df);
    int p = ptr_f[t] + atomicAdd(&cnt_f[t], 1);
    epk_f[2 * p] = s; epk_f[2 * p + 1] = __float_as_int(nwf);
    float db = deg_b[s];
    float nwb = w / ((db == 0.f) ? 1.f : db);
    int p2 = ptr_b[s] + atomicAdd(&cnt_b[s], 1);
    epk_b[2 * p2] = t; epk_b[2 * p2 + 1] = __float_as_int(nwb);
}

// ---------------- precompute W1 = enc_W @ Wih^T  [8][192] ----------------
__global__ void w1_k(const float* __restrict__ encW, const float* __restrict__ wih,
                     float* __restrict__ W1) {
    int id = blockIdx.x * 256 + threadIdx.x;
    if (id >= FF * GG) return;
    int f = id / GG, g = id - f * GG;
    float acc = 0.f;
    for (int hh = 0; hh < HH; hh++)
        acc = fmaf(encW[f * HH + hh], wih[g * HH + hh], acc);
    W1[id] = acc;
}

// ---- biasA[n][g] = bih[g] + (g<128? bhh[g]:0) + sum_h (enc_b+emb[n])*Wih[g][h] ----
__global__ __launch_bounds__(256, 2)
void biasA_k(const float* __restrict__ emb, const float* __restrict__ encb,
             const float* __restrict__ wih, const float* __restrict__ bih,
             const float* __restrict__ bhh, float* __restrict__ biasA) {
    __shared__ float wl[HH * GG];   // wl[h][g] = Wih[g][h]
    __shared__ float et[64 * 68];   // enc_b + emb tile
    const int tid = threadIdx.x;
    const int n0 = blockIdx.x * 64;
    for (int idx = tid * 4; idx < GG * HH; idx += 1024) {
        float4 v = *(const float4*)&wih[idx];
        int g = idx >> 6, hh = idx & 63;
        wl[hh * GG + g] = v.x;
        wl[(hh + 1) * GG + g] = v.y;
        wl[(hh + 2) * GG + g] = v.z;
        wl[(hh + 3) * GG + g] = v.w;
    }
    {
        int row = tid >> 2, cc = (tid & 3) * 16;
        int n = n0 + row;
        #pragma unroll
        for (int u = 0; u < 4; u++) {
            float4 e4 = (n < NN) ? *(const float4*)&emb[(size_t)n * HH + cc + u * 4]
                                 : make_float4(0.f, 0.f, 0.f, 0.f);
            float4 b4 = *(const float4*)&encb[cc + u * 4];
            *(float4*)&et[row * 68 + cc + u * 4] =
                make_float4(e4.x + b4.x, e4.y + b4.y, e4.z + b4.z, e4.w + b4.w);
        }
    }
    __syncthreads();
    const int r0 = (tid >> 4) * 4;
    #pragma unroll 1
    for (int p = 0; p < 3; p++) {
        const int c0 = p * 64 + (tid & 15) * 4;
        float acc[4][4];
        float4 bi = *(const float4*)&bih[c0];
        float4 bh = (c0 < 128) ? *(const float4*)&bhh[c0] : make_float4(0.f, 0.f, 0.f, 0.f);
        #pragma unroll
        for (int i = 0; i < 4; i++) {
            acc[i][0] = bi.x + bh.x; acc[i][1] = bi.y + bh.y;
            acc[i][2] = bi.z + bh.z; acc[i][3] = bi.w + bh.w;
        }
        #pragma unroll 4
        for (int k4 = 0; k4 < 64; k4 += 4) {
            float4 hv[4];
            #pragma unroll
            for (int i = 0; i < 4; i++)
                hv[i] = *(const float4*)&et[(r0 + i) * 68 + k4];
            #pragma unroll
            for (int kk = 0; kk < 4; kk++) {
                const float4 wv = *(const float4*)&wl[(k4 + kk) * GG + c0];
                #pragma unroll
                for (int i = 0; i < 4; i++) {
                    float a_ = f4c(hv[i], kk);
                    FMA4(acc[i], wv, a_);
                }
            }
        }
        #pragma unroll
        for (int i = 0; i < 4; i++) {
            int n = n0 + r0 + i;
            if (n < NN)
                *(float4*)&biasA[(size_t)n * GG + c0] =
                    make_float4(acc[i][0], acc[i][1], acc[i][2], acc[i][3]);
        }
    }
}

// ---------------- MFMA GRU: all 12 steps, no barriers in loop ----------------
// h_out written as [m][64] (m = b*NN + n), i.e. batch-major slabs for prop.
__global__ __launch_bounds__(256, 2)
void gru_k(const float* __restrict__ x, const float* __restrict__ biasA,
           const float* __restrict__ W1, const float* __restrict__ whh,
           const float* __restrict__ bhh, float* __restrict__ h_out) {
    __shared__ int   lds_B[24 * 64 * 4];   // Whh B-fragments, bf16 packed (24 KB)
    __shared__ float lds_h[4 * 16 * 68];   // per-wave h scratch fp32 (17.4 KB)

    const int tid = threadIdx.x;
    const int wave = tid >> 6, ln = tid & 63;
    const int quad = ln >> 4, lx = ln & 15;
    const int m0 = blockIdx.x * 64;
    const int woff = wave * 16 * 68;

    // stage Whh B-fragments: frag fid=(c*2+q): B[k = q*32 + (ln>>4)*8 + j][g = c*16 + (ln&15)]
    #pragma unroll
    for (int it = 0; it < 6; it++) {
        int slot = tid + it * 256;
        int fid = slot >> 6, l2 = slot & 63;
        int c = fid >> 1, q = fid & 1;
        int g = c * 16 + (l2 & 15);
        int k0 = q * 32 + ((l2 >> 4) & 3) * 8;
        const float* wp = whh + (size_t)g * HH + k0;
        float4 v0 = *(const float4*)wp;
        float4 v1 = *(const float4*)(wp + 4);
        float fv[8] = {v0.x, v0.y, v0.z, v0.w, v1.x, v1.y, v1.z, v1.w};
        *(int4*)&lds_B[slot * 4] = hi8(fv);
    }

    // W1 B-fragments in registers (K=32 padded; only k<8 real -> lanes 0-15)
    int4 w1f[12];
    #pragma unroll
    for (int j = 0; j < 12; j++) w1f[j] = make_int4(0, 0, 0, 0);
    if (ln < 16) {
        #pragma unroll
        for (int j = 0; j < 12; j++) {
            int col = j * 16 + ln;
            float fv[8];
            #pragma unroll
            for (int k = 0; k < 8; k++) fv[k] = W1[k * GG + col];
            w1f[j] = hi8(fv);
        }
    }

    // per-lane biases (C-layout positions)
    f4v bR[4], bZ[4], bNx[4];
    float bHn[4];
    int rown[4];
    #pragma unroll
    for (int reg = 0; reg < 4; reg++) {
        int m = m0 + wave * 16 + quad * 4 + reg;
        int b = m / NN; rown[reg] = m - b * NN;
    }
    #pragma unroll
    for (int j = 0; j < 4; j++) {
        int c = j * 16 + lx;
        #pragma unroll
        for (int reg = 0; reg < 4; reg++) {
            const float* bp = biasA + (size_t)rown[reg] * GG;
            bR[j][reg]  = bp[c];
            bZ[j][reg]  = bp[64 + c];
            bNx[j][reg] = bp[128 + c];
        }
        bHn[j] = bhh[128 + c];
    }

    __syncthreads();   // lds_B ready (only barrier)

    f4v hp[4];
    #pragma unroll
    for (int j = 0; j < 4; j++) hp[j] = (f4v){0.f, 0.f, 0.f, 0.f};

    #pragma unroll 1
    for (int t = 0; t < TT; t++) {
        // x A-fragment (lanes 0-15 hold k=0..7), hi/lo
        int4 axh = make_int4(0,0,0,0), axl = make_int4(0,0,0,0);
        if (ln < 16) {
            int m = m0 + wave * 16 + ln;
            int b = m / NN; int n = m - b * NN;
            const float* xp = x + ((size_t)(b * TT + t) * NN + n) * FF;
            float4 v0 = *(const float4*)xp;
            float4 v1 = *(const float4*)(xp + 4);
            float fv[8] = {v0.x, v0.y, v0.z, v0.w, v1.x, v1.y, v1.z, v1.w};
            hilo8(fv, axh, axl);
        }

        // h A-fragments (2 K-halves), single bf16 rounding
        int4 ahf[2];
        if (t) {
            #pragma unroll
            for (int q = 0; q < 2; q++) {
                const float* hp_ = &lds_h[woff + lx * 68 + q * 32 + quad * 8];
                float4 v0 = *(const float4*)hp_;
                float4 v1 = *(const float4*)(hp_ + 4);
                float fv[8] = {v0.x, v0.y, v0.z, v0.w, v1.x, v1.y, v1.z, v1.w};
                ahf[q] = hi8(fv);
            }
        }

        f4v accR[4], accZ[4], accNx[4], accNh[4];
        #pragma unroll
        for (int j = 0; j < 4; j++) {
            accR[j]  = mfma16(axh, w1f[j],     mfma16(axl, w1f[j],     bR[j]));
            accZ[j]  = mfma16(axh, w1f[j + 4], mfma16(axl, w1f[j + 4], bZ[j]));
            accNx[j] = mfma16(axh, w1f[j + 8], mfma16(axl, w1f[j + 8], bNx[j]));
            accNh[j] = (f4v){bHn[j], bHn[j], bHn[j], bHn[j]};
        }
        if (t) {
            #pragma unroll
            for (int j = 0; j < 4; j++) {
                #pragma unroll
                for (int q = 0; q < 2; q++) {
                    int4 bRf = *(const int4*)&lds_B[((j * 2 + q) * 64 + ln) * 4];
                    int4 bZf = *(const int4*)&lds_B[(((j + 4) * 2 + q) * 64 + ln) * 4];
                    int4 bNf = *(const int4*)&lds_B[(((j + 8) * 2 + q) * 64 + ln) * 4];
                    accR[j]  = mfma16(ahf[q], bRf, accR[j]);
                    accZ[j]  = mfma16(ahf[q], bZf, accZ[j]);
                    accNh[j] = mfma16(ahf[q], bNf, accNh[j]);
                }
            }
        }

        // gates + h write (per-wave private LDS region; same-wave DS in-order)
        #pragma unroll
        for (int j = 0; j < 4; j++) {
            #pragma unroll
            for (int reg = 0; reg < 4; reg++) {
                float rr = 1.f / (1.f + __expf(-accR[j][reg]));
                float zz = 1.f / (1.f + __expf(-accZ[j][reg]));
                float pre = fmaf(rr, accNh[j][reg], accNx[j][reg]);
                pre = fminf(fmaxf(pre, -30.f), 30.f);
                float e2 = __expf(pre + pre);
                float nn = (e2 - 1.f) / (e2 + 1.f);
                float hv = (1.f - zz) * nn + zz * hp[j][reg];
                hp[j][reg] = hv;
                lds_h[woff + (quad * 4 + reg) * 68 + j * 16 + lx] = hv;
            }
        }
    }
    __syncthreads();   // all waves done writing their final h

    // epilogue: coalesced write to h_out[m][64]
    {
        int row = ln >> 2, cc = (ln & 3) * 16;
        int m = m0 + wave * 16 + row;
        float* op = h_out + (size_t)m * HH + cc;
        #pragma unroll
        for (int u = 0; u < 4; u++) {
            float4 v = *(const float4*)&lds_h[woff + row * 68 + cc + u * 4];
            *(float4*)(op + u * 4) = v;
        }
    }
}

// ---------------- diffusion: batch-chunked, L2-resident gathers ----------------
// grid (2500, 8 batches, 2 dirs); wave = one (node, batch); lane = channel.
// Source slab per (batch) = NN*HH*4 = 2.56 MB -> fits per-XCD L2.
__global__ __launch_bounds__(256)
void prop_k(const float* __restrict__ srcF, float* __restrict__ dstF,
            const int* __restrict__ ptrF, const int2* __restrict__ epkF,
            const float* __restrict__ srcB, float* __restrict__ dstB,
            const int* __restrict__ ptrB, const int2* __restrict__ epkB) {
    const int wv = threadIdx.x >> 6;
    const int ln = threadIdx.x & 63;
    const int node = blockIdx.x * 4 + wv;
    const int b = blockIdx.y;
    const float* src; float* dst; const int* ptr; const int2* ep;
    if (blockIdx.z == 0) { src = srcF; dst = dstF; ptr = ptrF; ep = epkF; }
    else                 { src = srcB; dst = dstB; ptr = ptrB; ep = epkB; }
    const float* sb = src + (size_t)b * (NN * HH) + ln;
    float acc = 0.f;
    int e0 = ptr[node], e1 = ptr[node + 1];
    for (int e = e0; e < e1; e++) {
        int2 v = ep[e];                       // wave-uniform scalar load
        acc = fmaf(sb[(size_t)v.x * HH], __int_as_float(v.y), acc);
    }
    dst[((size_t)b * NN + node) * HH + ln] = acc;
}

// ---------------- fused filter (K=320) + decoder (K=64) ----------------
__global__ __launch_bounds__(256, 2)
void filtdec_k(const float* __restrict__ h, const float* __restrict__ f1,
               const float* __restrict__ f2, const float* __restrict__ b1,
               const float* __restrict__ b2,
               const float* __restrict__ filtW, const float* __restrict__ filtb,
               const float* __restrict__ decW, const float* __restrict__ decb,
               float* __restrict__ out) {
    __shared__ float lds_in[64 * 100];
    __shared__ float lds_w[64 * 100];
    __shared__ float lds_z[64 * 68];
    const int tid = threadIdx.x;
    const int m0 = blockIdx.x * 64;
    const int c0 = (tid & 15) * 4, r0 = (tid >> 4) * 4;

    float acc[4][4];
    #pragma unroll
    for (int i = 0; i < 4; i++)
        #pragma unroll
        for (int j = 0; j < 4; j++) acc[i][j] = 0.f;

    #pragma unroll 1
    for (int q = 0; q < 5; q++) {
        const float* src = (q == 0) ? h : (q == 1) ? f1 : (q == 2) ? f2 : (q == 3) ? b1 : b2;
        {   // load input tile 64x64 fp32 ([m][64] rows)
            int row = tid >> 2, cc = (tid & 3) * 16;
            const float* sp = src + (size_t)(m0 + row) * HH + cc;
            float4 v0 = *(const float4*)(sp + 0);
            float4 v1 = *(const float4*)(sp + 4);
            float4 v2 = *(const float4*)(sp + 8);
            float4 v3 = *(const float4*)(sp + 12);
            *(float4*)&lds_in[row * 100 + cc + 0]  = v0;
            *(float4*)&lds_in[row * 100 + cc + 4]  = v1;
            *(float4*)&lds_in[row * 100 + cc + 8]  = v2;
            *(float4*)&lds_in[row * 100 + cc + 12] = v3;
        }
        {   // load filtW chunk rows q*64..
            int k = tid >> 2, cc = (tid & 3) * 16;
            const float* wp = filtW + (size_t)(q * 64 + k) * HH + cc;
            float4 v0 = *(const float4*)(wp + 0);
            float4 v1 = *(const float4*)(wp + 4);
            float4 v2 = *(const float4*)(wp + 8);
            float4 v3 = *(const float4*)(wp + 12);
            *(float4*)&lds_w[k * 100 + cc + 0]  = v0;
            *(float4*)&lds_w[k * 100 + cc + 4]  = v1;
            *(float4*)&lds_w[k * 100 + cc + 8]  = v2;
            *(float4*)&lds_w[k * 100 + cc + 12] = v3;
        }
        __syncthreads();
        #pragma unroll 4
        for (int k4 = 0; k4 < 64; k4 += 4) {
            float4 iv[4];
            #pragma unroll
            for (int i = 0; i < 4; i++)
                iv[i] = *(const float4*)&lds_in[(r0 + i) * 100 + k4];
            #pragma unroll
            for (int kk = 0; kk < 4; kk++) {
                const float4 wv = *(const float4*)&lds_w[(k4 + kk) * 100 + c0];
                #pragma unroll
                for (int i = 0; i < 4; i++) {
                    float a_ = f4c(iv[i], kk);
                    FMA4(acc[i], wv, a_);
                }
            }
        }
        __syncthreads();
    }
    {
        float fb[4];
        #pragma unroll
        for (int j = 0; j < 4; j++) fb[j] = filtb[c0 + j];
        #pragma unroll
        for (int i = 0; i < 4; i++)
            *(float4*)&lds_z[(r0 + i) * 68 + c0] =
                make_float4(acc[i][0] + fb[0], acc[i][1] + fb[1],
                            acc[i][2] + fb[2], acc[i][3] + fb[3]);
    }
    {   // load decW [64][96]
        int k = tid >> 2, cc = (tid & 3) * 24;
        const float* wp = decW + k * 96 + cc;
        float* dstp = &lds_w[k * 100 + cc];
        #pragma unroll
        for (int u = 0; u < 6; u++) {
            float4 v = *(const float4*)(wp + u * 4);
            *(float4*)(dstp + u * 4) = v;
        }
    }
    __syncthreads();

    const int c0b = (tid & 15) * 6;
    float acc2[4][6];
    #pragma unroll
    for (int i = 0; i < 4; i++)
        #pragma unroll
        for (int j = 0; j < 6; j++) acc2[i][j] = 0.f;
    #pragma unroll 4
    for (int k4 = 0; k4 < 64; k4 += 4) {
        float4 zv[4];
        #pragma unroll
        for (int i = 0; i < 4; i++)
            zv[i] = *(const float4*)&lds_z[(r0 + i) * 68 + k4];
        #pragma unroll
        for (int kk = 0; kk < 4; kk++) {
            float2 wa = *(const float2*)&lds_w[(k4 + kk) * 100 + c0b];
            float2 wb = *(const float2*)&lds_w[(k4 + kk) * 100 + c0b + 2];
            float2 wc = *(const float2*)&lds_w[(k4 + kk) * 100 + c0b + 4];
            #pragma unroll
            for (int i = 0; i < 4; i++) {
                float zz = f4c(zv[i], kk);
                acc2[i][0] = fmaf(zz, wa.x, acc2[i][0]);
                acc2[i][1] = fmaf(zz, wa.y, acc2[i][1]);
                acc2[i][2] = fmaf(zz, wb.x, acc2[i][2]);
                acc2[i][3] = fmaf(zz, wb.y, acc2[i][3]);
                acc2[i][4] = fmaf(zz, wc.x, acc2[i][4]);
                acc2[i][5] = fmaf(zz, wc.y, acc2[i][5]);
            }
        }
    }
    {
        float db[6];
        #pragma unroll
        for (int j = 0; j < 6; j++) db[j] = decb[c0b + j];
        #pragma unroll
        for (int i = 0; i < 4; i++)
            #pragma unroll
            for (int j = 0; j < 6; j++)
                lds_in[(r0 + i) * 100 + c0b + j] = acc2[i][j] + db[j];
    }
    __syncthreads();
    #pragma unroll 1
    for (int hor = 0; hor < HORZ; hor++) {
        int nl = tid >> 2, fp = tid & 3;
        int m = m0 + nl;
        int b = m / NN; int n = m - b * NN;
        float v0 = lds_in[nl * 100 + hor * 8 + 2 * fp];
        float v1 = lds_in[nl * 100 + hor * 8 + 2 * fp + 1];
        *(float2*)&out[(((size_t)b * HORZ + hor) * NN + n) * FF + 2 * fp] =
            make_float2(v0, v1);
    }
}

extern "C" void kernel_launch(void* const* d_in, const int* in_sizes, int n_in,
                              void* d_out, int out_size, void* d_ws, size_t ws_size,
                              hipStream_t stream) {
    (void)in_sizes; (void)n_in; (void)out_size; (void)ws_size;
    const float* x     = (const float*)d_in[0];
    const int*   ei    = (const int*)d_in[1];
    const float* ew    = (const float*)d_in[2];
    const float* encW  = (const float*)d_in[3];
    const float* encb  = (const float*)d_in[4];
    const float* emb   = (const float*)d_in[5];
    const float* wih   = (const float*)d_in[6];
    const float* whh   = (const float*)d_in[7];
    const float* bih   = (const float*)d_in[8];
    const float* bhh   = (const float*)d_in[9];
    const float* filtW = (const float*)d_in[10];
    const float* filtb = (const float*)d_in[11];
    const float* decW  = (const float*)d_in[12];
    const float* decb  = (const float*)d_in[13];
    float* out = (float*)d_out;

    float* ws = (float*)d_ws;
    float* h    = ws + OFF_H;
    float* f1   = ws + OFF_F1;
    float* f2   = ws + OFF_F2;
    float* b1   = ws + OFF_B1;
    float* b2   = ws + OFF_B2;
    float* bias = ws + OFF_BIAS;
    float* W1   = ws + OFF_W1;
    float* degf = ws + OFF_DEGF;
    float* degb = ws + OFF_DEGB;
    int* cntf = (int*)(ws + OFF_CNTF);
    int* cntb = (int*)(ws + OFF_CNTB);
    int* ptrf = (int*)(ws + OFF_PTRF);
    int* ptrb = (int*)(ws + OFF_PTRB);
    int* epkf = (int*)(ws + OFF_EPKF);
    int* epkb = (int*)(ws + OFF_EPKB);
    int* flag = (int*)(ws + OFF_FLAG);

    flag_k<<<1, 64, 0, stream>>>(ei, flag);
    zero_k<<<(40000 + 255) / 256, 256, 0, stream>>>(degf, 40000);
    csr_count_k<<<EE / 256, 256, 0, stream>>>(ei, ew, flag, cntf, cntb, degf, degb);
    scan_k<<<2, 256, 0, stream>>>(cntf, cntb, ptrf, ptrb);
    csr_fill_k<<<EE / 256, 256, 0, stream>>>(ei, ew, flag, degf, degb, ptrf, ptrb,
                                             cntf, cntb, epkf, epkb);
    w1_k<<<(FF * GG + 255) / 256, 256, 0, stream>>>(encW, wih, W1);
    biasA_k<<<(NN + 63) / 64, 256, 0, stream>>>(emb, encb, wih, bih, bhh, bias);
    gru_k<<<MM / 64, 256, 0, stream>>>(x, bias, W1, whh, bhh, h);
    {
        dim3 g(NN / 4, BB, 2);
        prop_k<<<g, 256, 0, stream>>>(h,  f1, ptrf, (const int2*)epkf,
                                      h,  b1, ptrb, (const int2*)epkb);
        prop_k<<<g, 256, 0, stream>>>(f1, f2, ptrf, (const int2*)epkf,
                                      b1, b2, ptrb, (const int2*)epkb);
    }
    filtdec_k<<<MM / 64, 256, 0, stream>>>(h, f1, f2, b1, b2,
                                           filtW, filtb, decW, decb, out);
}

// Round 6
// 867.987 us; speedup vs baseline: 1.3978x; 1.3978x over previous
//
#include <hip/hip_runtime.h>

typedef unsigned short ushort_t;

#define NN 10000
#define BB 8
#define TT 12
#define FF 8
#define HH 64
#define GG 192   // 3H
#define HORZ 12
#define EE 320000
#define MM (BB*NN) // 80000

// ---- ws layout (float words) ----
#define OFF_H    0u
#define OFF_F1   5120000u
#define OFF_F2   10240000u
#define OFF_B1   15360000u
#define OFF_B2   20480000u
#define OFF_BIAS 25600000u
#define OFF_W1   27520000u
#define OFF_DEGF 27521536u
#define OFF_DEGB 27531536u
#define OFF_CNTF 27541536u
#define OFF_CNTB 27551536u
#define OFF_PTRF 27561536u
#define OFF_PTRB 27571537u
#define OFF_EPKF 27581538u   // packed (idx, w) int2 per edge, fwd (640000 words)
#define OFF_EPKB 28221538u   // packed (idx, w) int2 per edge, bwd (640000 words)
#define OFF_FLAG 28861538u

typedef __attribute__((ext_vector_type(8))) short short8;
typedef __attribute__((ext_vector_type(4))) float f4v;

union I4S8 { int4 i; short8 s; };

__device__ __forceinline__ f4v mfma16(int4 a, int4 b, f4v c) {
    I4S8 ua, ub; ua.i = a; ub.i = b;
    return __builtin_amdgcn_mfma_f32_16x16x32_bf16(ua.s, ub.s, c, 0, 0, 0);
}

__device__ __forceinline__ unsigned f2bf_u(float f) {
    union { float f; unsigned u; } v; v.f = f;
    unsigned x = v.u;
    x += 0x7FFFu + ((x >> 16) & 1u);
    return x >> 16;
}
// split 8 fp32 into bf16 hi + bf16 lo fragments (packed)
__device__ __forceinline__ void hilo8(const float* f, int4& hi, int4& lo) {
    unsigned hb[8], lb[8];
    #pragma unroll
    for (int i = 0; i < 8; i++) {
        float v = f[i];
        unsigned h = f2bf_u(v);
        union { unsigned u; float fl; } bk; bk.u = h << 16;
        lb[i] = f2bf_u(v - bk.fl);
        hb[i] = h;
    }
    hi = make_int4((int)(hb[0]|(hb[1]<<16)), (int)(hb[2]|(hb[3]<<16)),
                   (int)(hb[4]|(hb[5]<<16)), (int)(hb[6]|(hb[7]<<16)));
    lo = make_int4((int)(lb[0]|(lb[1]<<16)), (int)(lb[2]|(lb[3]<<16)),
                   (int)(lb[4]|(lb[5]<<16)), (int)(lb[6]|(lb[7]<<16)));
}
// pack 8 fp32 -> bf16 (round-to-nearest) fragment
__device__ __forceinline__ int4 hi8(const float* f) {
    unsigned hb[8];
    #pragma unroll
    for (int i = 0; i < 8; i++) hb[i] = f2bf_u(f[i]);
    return make_int4((int)(hb[0]|(hb[1]<<16)), (int)(hb[2]|(hb[3]<<16)),
                     (int)(hb[4]|(hb[5]<<16)), (int)(hb[6]|(hb[7]<<16)));
}

__device__ __forceinline__ float f4c(const float4& v, int kk) {
    switch (kk) { case 0: return v.x; case 1: return v.y; case 2: return v.z; default: return v.w; }
}
#define FMA4(ACC, W, S) \
    ACC[0] = fmaf(S, W.x, ACC[0]); \
    ACC[1] = fmaf(S, W.y, ACC[1]); \
    ACC[2] = fmaf(S, W.z, ACC[2]); \
    ACC[3] = fmaf(S, W.w, ACC[3]);

// ---------------- utility ----------------
__global__ void zero_k(float* p, int n) {
    int i = blockIdx.x * 256 + threadIdx.x;
    if (i < n) p[i] = 0.f;
}

__global__ void flag_k(const int* __restrict__ ei, int* flag) {
    if (threadIdx.x == 0 && blockIdx.x == 0) {
        int o = ei[1] | ei[3] | ei[5] | ei[7] | ei[9] | ei[11] | ei[13];
        flag[0] = (o == 0) ? 1 : 0;
    }
}

__device__ __forceinline__ void load_edge(const int* __restrict__ ei, int isI64,
                                          int e, int& s, int& t) {
    if (isI64) {
        const long long* p = (const long long*)ei;
        s = (int)p[e]; t = (int)p[EE + e];
    } else {
        s = ei[e]; t = ei[EE + e];
    }
}

// ---------------- CSR build ----------------
__global__ void csr_count_k(const int* __restrict__ ei, const float* __restrict__ ew,
                            const int* __restrict__ flag,
                            int* cnt_f, int* cnt_b, float* deg_f, float* deg_b) {
    int e = blockIdx.x * 256 + threadIdx.x;
    if (e >= EE) return;
    int isI64 = flag[0];
    int s, t; load_edge(ei, isI64, e, s, t);
    if ((unsigned)s >= NN || (unsigned)t >= NN) return;
    float w = ew[e];
    atomicAdd(&cnt_f[t], 1); atomicAdd(&deg_f[t], w);
    atomicAdd(&cnt_b[s], 1); atomicAdd(&deg_b[s], w);
}

__global__ void scan_k(int* cnt_f, int* cnt_b, int* ptr_f, int* ptr_b) {
    int* cnt = blockIdx.x ? cnt_b : cnt_f;
    int* ptr = blockIdx.x ? ptr_b : ptr_f;
    __shared__ int part[256];
    int tid = threadIdx.x;
    const int CH = (NN + 255) / 256;
    int lo = tid * CH, hi = lo + CH; if (hi > NN) hi = NN; if (lo > NN) lo = NN;
    int s = 0;
    for (int i = lo; i < hi; i++) s += cnt[i];
    part[tid] = s;
    __syncthreads();
    if (tid == 0) {
        int run = 0;
        for (int i = 0; i < 256; i++) { int v = part[i]; part[i] = run; run += v; }
        ptr[NN] = run;
    }
    __syncthreads();
    int run = part[tid];
    for (int i = lo; i < hi; i++) { ptr[i] = run; run += cnt[i]; cnt[i] = 0; }
}

__global__ void csr_fill_k(const int* __restrict__ ei, const float* __restrict__ ew,
                           const int* __restrict__ flag,
                           const float* __restrict__ deg_f, const float* __restrict__ deg_b,
                           const int* __restrict__ ptr_f, const int* __restrict__ ptr_b,
                           int* cnt_f, int* cnt_b,
                           int* epk_f, int* epk_b) {
    int e = blockIdx.x * 256 + threadIdx.x;
    if (e >= EE) return;
    int isI64 = flag[0];
    int s, t; load_edge(ei, isI64, e, s, t);
    if ((unsigned)s >= NN || (unsigned)t >= NN) return;
    float w = ew[e];
    float df = deg_f[t];
    float nwf = w / ((df == 0.f) ? 1.f : df);
    int p = ptr_f[t] + atomicAdd(&cnt_f[t], 1);
    epk_f[2 * p] = s; epk_f[2 * p + 1] = __float_as_int(nwf);
    float db = deg_b[s];
    float nwb = w / ((db == 0.f) ? 1.f : db);
    int p2 = ptr_b[s] + atomicAdd(&cnt_b[s], 1);
    epk_b[2 * p2] = t; epk_b[2 * p2 + 1] = __float_as_int(nwb);
}

// ---------------- precompute W1 = enc_W @ Wih^T  [8][192] ----------------
__global__ void w1_k(const float* __restrict__ encW, const float* __restrict__ wih,
                     float* __restrict__ W1) {
    int id = blockIdx.x * 256 + threadIdx.x;
    if (id >= FF * GG) return;
    int f = id / GG, g = id - f * GG;
    float acc = 0.f;
    for (int hh = 0; hh < HH; hh++)
        acc = fmaf(encW[f * HH + hh], wih[g * HH + hh], acc);
    W1[id] = acc;
}

// ---- biasA[n][g] = bih[g] + (g<128? bhh[g]:0) + sum_h (enc_b+emb[n])*Wih[g][h] ----
__global__ __launch_bounds__(256, 2)
void biasA_k(const float* __restrict__ emb, const float* __restrict__ encb,
             const float* __restrict__ wih, const float* __restrict__ bih,
             const float* __restrict__ bhh, float* __restrict__ biasA) {
    __shared__ float wl[HH * GG];   // wl[h][g] = Wih[g][h]
    __shared__ float et[64 * 68];   // enc_b + emb tile
    const int tid = threadIdx.x;
    const int n0 = blockIdx.x * 64;
    for (int idx = tid * 4; idx < GG * HH; idx += 1024) {
        float4 v = *(const float4*)&wih[idx];
        int g = idx >> 6, hh = idx & 63;
        wl[hh * GG + g] = v.x;
        wl[(hh + 1) * GG + g] = v.y;
        wl[(hh + 2) * GG + g] = v.z;
        wl[(hh + 3) * GG + g] = v.w;
    }
    {
        int row = tid >> 2, cc = (tid & 3) * 16;
        int n = n0 + row;
        #pragma unroll
        for (int u = 0; u < 4; u++) {
            float4 e4 = (n < NN) ? *(const float4*)&emb[(size_t)n * HH + cc + u * 4]
                                 : make_float4(0.f, 0.f, 0.f, 0.f);
            float4 b4 = *(const float4*)&encb[cc + u * 4];
            *(float4*)&et[row * 68 + cc + u * 4] =
                make_float4(e4.x + b4.x, e4.y + b4.y, e4.z + b4.z, e4.w + b4.w);
        }
    }
    __syncthreads();
    const int r0 = (tid >> 4) * 4;
    #pragma unroll 1
    for (int p = 0; p < 3; p++) {
        const int c0 = p * 64 + (tid & 15) * 4;
        float acc[4][4];
        float4 bi = *(const float4*)&bih[c0];
        float4 bh = (c0 < 128) ? *(const float4*)&bhh[c0] : make_float4(0.f, 0.f, 0.f, 0.f);
        #pragma unroll
        for (int i = 0; i < 4; i++) {
            acc[i][0] = bi.x + bh.x; acc[i][1] = bi.y + bh.y;
            acc[i][2] = bi.z + bh.z; acc[i][3] = bi.w + bh.w;
        }
        #pragma unroll 4
        for (int k4 = 0; k4 < 64; k4 += 4) {
            float4 hv[4];
            #pragma unroll
            for (int i = 0; i < 4; i++)
                hv[i] = *(const float4*)&et[(r0 + i) * 68 + k4];
            #pragma unroll
            for (int kk = 0; kk < 4; kk++) {
                const float4 wv = *(const float4*)&wl[(k4 + kk) * GG + c0];
                #pragma unroll
                for (int i = 0; i < 4; i++) {
                    float a_ = f4c(hv[i], kk);
                    FMA4(acc[i], wv, a_);
                }
            }
        }
        #pragma unroll
        for (int i = 0; i < 4; i++) {
            int n = n0 + r0 + i;
            if (n < NN)
                *(float4*)&biasA[(size_t)n * GG + c0] =
                    make_float4(acc[i][0], acc[i][1], acc[i][2], acc[i][3]);
        }
    }
}

// ---------------- MFMA GRU: all 12 steps, no barriers in loop ----------------
// h_out written as [m][64] (m = b*NN + n), i.e. batch-major slabs for prop.
__global__ __launch_bounds__(256, 2)
void gru_k(const float* __restrict__ x, const float* __restrict__ biasA,
           const float* __restrict__ W1, const float* __restrict__ whh,
           const float* __restrict__ bhh, float* __restrict__ h_out) {
    __shared__ int   lds_B[24 * 64 * 4];   // Whh B-fragments, bf16 packed (24 KB)
    __shared__ float lds_h[4 * 16 * 68];   // per-wave h scratch fp32 (17.4 KB)

    const int tid = threadIdx.x;
    const int wave = tid >> 6, ln = tid & 63;
    const int quad = ln >> 4, lx = ln & 15;
    const int m0 = blockIdx.x * 64;
    const int woff = wave * 16 * 68;

    // stage Whh B-fragments: frag fid=(c*2+q): B[k = q*32 + (ln>>4)*8 + j][g = c*16 + (ln&15)]
    #pragma unroll
    for (int it = 0; it < 6; it++) {
        int slot = tid + it * 256;
        int fid = slot >> 6, l2 = slot & 63;
        int c = fid >> 1, q = fid & 1;
        int g = c * 16 + (l2 & 15);
        int k0 = q * 32 + ((l2 >> 4) & 3) * 8;
        const float* wp = whh + (size_t)g * HH + k0;
        float4 v0 = *(const float4*)wp;
        float4 v1 = *(const float4*)(wp + 4);
        float fv[8] = {v0.x, v0.y, v0.z, v0.w, v1.x, v1.y, v1.z, v1.w};
        *(int4*)&lds_B[slot * 4] = hi8(fv);
    }

    // W1 B-fragments in registers (K=32 padded; only k<8 real -> lanes 0-15)
    int4 w1f[12];
    #pragma unroll
    for (int j = 0; j < 12; j++) w1f[j] = make_int4(0, 0, 0, 0);
    if (ln < 16) {
        #pragma unroll
        for (int j = 0; j < 12; j++) {
            int col = j * 16 + ln;
            float fv[8];
            #pragma unroll
            for (int k = 0; k < 8; k++) fv[k] = W1[k * GG + col];
            w1f[j] = hi8(fv);
        }
    }

    // per-lane biases (C-layout positions)
    f4v bR[4], bZ[4], bNx[4];
    float bHn[4];
    int rown[4];
    #pragma unroll
    for (int reg = 0; reg < 4; reg++) {
        int m = m0 + wave * 16 + quad * 4 + reg;
        int b = m / NN; rown[reg] = m - b * NN;
    }
    #pragma unroll
    for (int j = 0; j < 4; j++) {
        int c = j * 16 + lx;
        #pragma unroll
        for (int reg = 0; reg < 4; reg++) {
            const float* bp = biasA + (size_t)rown[reg] * GG;
            bR[j][reg]  = bp[c];
            bZ[j][reg]  = bp[64 + c];
            bNx[j][reg] = bp[128 + c];
        }
        bHn[j] = bhh[128 + c];
    }

    __syncthreads();   // lds_B ready (only barrier)

    f4v hp[4];
    #pragma unroll
    for (int j = 0; j < 4; j++) hp[j] = (f4v){0.f, 0.f, 0.f, 0.f};

    #pragma unroll 1
    for (int t = 0; t < TT; t++) {
        // x A-fragment (lanes 0-15 hold k=0..7), hi/lo
        int4 axh = make_int4(0,0,0,0), axl = make_int4(0,0,0,0);
        if (ln < 16) {
            int m = m0 + wave * 16 + ln;
            int b = m / NN; int n = m - b * NN;
            const float* xp = x + ((size_t)(b * TT + t) * NN + n) * FF;
            float4 v0 = *(const float4*)xp;
            float4 v1 = *(const float4*)(xp + 4);
            float fv[8] = {v0.x, v0.y, v0.z, v0.w, v1.x, v1.y, v1.z, v1.w};
            hilo8(fv, axh, axl);
        }

        // h A-fragments (2 K-halves), single bf16 rounding
        int4 ahf[2];
        if (t) {
            #pragma unroll
            for (int q = 0; q < 2; q++) {
                const float* hp_ = &lds_h[woff + lx * 68 + q * 32 + quad * 8];
                float4 v0 = *(const float4*)hp_;
                float4 v1 = *(const float4*)(hp_ + 4);
                float fv[8] = {v0.x, v0.y, v0.z, v0.w, v1.x, v1.y, v1.z, v1.w};
                ahf[q] = hi8(fv);
            }
        }

        f4v accR[4], accZ[4], accNx[4], accNh[4];
        #pragma unroll
        for (int j = 0; j < 4; j++) {
            accR[j]  = mfma16(axh, w1f[j],     mfma16(axl, w1f[j],     bR[j]));
            accZ[j]  = mfma16(axh, w1f[j + 4], mfma16(axl, w1f[j + 4], bZ[j]));
            accNx[j] = mfma16(axh, w1f[j + 8], mfma16(axl, w1f[j + 8], bNx[j]));
            accNh[j] = (f4v){bHn[j], bHn[j], bHn[j], bHn[j]};
        }
        if (t) {
            #pragma unroll
            for (int j = 0; j < 4; j++) {
                #pragma unroll
                for (int q = 0; q < 2; q++) {
                    int4 bRf = *(const int4*)&lds_B[((j * 2 + q) * 64 + ln) * 4];
                    int4 bZf = *(const int4*)&lds_B[(((j + 4) * 2 + q) * 64 + ln) * 4];
                    int4 bNf = *(const int4*)&lds_B[(((j + 8) * 2 + q) * 64 + ln) * 4];
                    accR[j]  = mfma16(ahf[q], bRf, accR[j]);
                    accZ[j]  = mfma16(ahf[q], bZf, accZ[j]);
                    accNh[j] = mfma16(ahf[q], bNf, accNh[j]);
                }
            }
        }

        // gates + h write (per-wave private LDS region; same-wave DS in-order)
        #pragma unroll
        for (int j = 0; j < 4; j++) {
            #pragma unroll
            for (int reg = 0; reg < 4; reg++) {
                float rr = 1.f / (1.f + __expf(-accR[j][reg]));
                float zz = 1.f / (1.f + __expf(-accZ[j][reg]));
                float pre = fmaf(rr, accNh[j][reg], accNx[j][reg]);
                pre = fminf(fmaxf(pre, -30.f), 30.f);
                float e2 = __expf(pre + pre);
                float nn = (e2 - 1.f) / (e2 + 1.f);
                float hv = (1.f - zz) * nn + zz * hp[j][reg];
                hp[j][reg] = hv;
                lds_h[woff + (quad * 4 + reg) * 68 + j * 16 + lx] = hv;
            }
        }
    }
    __syncthreads();   // all waves done writing their final h

    // epilogue: coalesced write to h_out[m][64]
    {
        int row = ln >> 2, cc = (ln & 3) * 16;
        int m = m0 + wave * 16 + row;
        float* op = h_out + (size_t)m * HH + cc;
        #pragma unroll
        for (int u = 0; u < 4; u++) {
            float4 v = *(const float4*)&lds_h[woff + row * 68 + cc + u * 4];
            *(float4*)(op + u * 4) = v;
        }
    }
}

// ---------------- diffusion: batch-chunked, L2-resident gathers ----------------
// grid (2500, 8 batches, 2 dirs); wave = one (node, batch); lane = channel.
// Source slab per batch = NN*HH*4 = 2.56 MB -> fits per-XCD L2. Edge records
// and dst stores are NON-TEMPORAL so they don't evict the slab from L2.
__global__ __launch_bounds__(256)
void prop_k(const float* __restrict__ srcF, float* __restrict__ dstF,
            const int* __restrict__ ptrF, const long long* __restrict__ epkF,
            const float* __restrict__ srcB, float* __restrict__ dstB,
            const int* __restrict__ ptrB, const long long* __restrict__ epkB) {
    const int wv = threadIdx.x >> 6;
    const int ln = threadIdx.x & 63;
    const int node = blockIdx.x * 4 + wv;
    const int b = blockIdx.y;
    const float* src; float* dst; const int* ptr; const long long* ep;
    if (blockIdx.z == 0) { src = srcF; dst = dstF; ptr = ptrF; ep = epkF; }
    else                 { src = srcB; dst = dstB; ptr = ptrB; ep = epkB; }
    const float* sb = src + (size_t)b * (NN * HH) + ln;
    const int e0 = ptr[node], e1 = ptr[node + 1];
    float ac0 = 0.f, ac1 = 0.f, ac2 = 0.f, ac3 = 0.f;
    int e = e0;
    for (; e + 4 <= e1; e += 4) {
        long long p0 = __builtin_nontemporal_load(&ep[e]);
        long long p1 = __builtin_nontemporal_load(&ep[e + 1]);
        long long p2 = __builtin_nontemporal_load(&ep[e + 2]);
        long long p3 = __builtin_nontemporal_load(&ep[e + 3]);
        float g0 = sb[(size_t)(int)p0 * HH];
        float g1 = sb[(size_t)(int)p1 * HH];
        float g2 = sb[(size_t)(int)p2 * HH];
        float g3 = sb[(size_t)(int)p3 * HH];
        ac0 = fmaf(g0, __int_as_float((int)(p0 >> 32)), ac0);
        ac1 = fmaf(g1, __int_as_float((int)(p1 >> 32)), ac1);
        ac2 = fmaf(g2, __int_as_float((int)(p2 >> 32)), ac2);
        ac3 = fmaf(g3, __int_as_float((int)(p3 >> 32)), ac3);
    }
    for (; e < e1; e++) {
        long long p0 = __builtin_nontemporal_load(&ep[e]);
        ac0 = fmaf(sb[(size_t)(int)p0 * HH], __int_as_float((int)(p0 >> 32)), ac0);
    }
    float acc = (ac0 + ac1) + (ac2 + ac3);
    __builtin_nontemporal_store(acc, &dst[((size_t)b * NN + node) * HH + ln]);
}

// ---------------- fused filter (K=320) + decoder (K=64) ----------------
__global__ __launch_bounds__(256, 2)
void filtdec_k(const float* __restrict__ h, const float* __restrict__ f1,
               const float* __restrict__ f2, const float* __restrict__ b1,
               const float* __restrict__ b2,
               const float* __restrict__ filtW, const float* __restrict__ filtb,
               const float* __restrict__ decW, const float* __restrict__ decb,
               float* __restrict__ out) {
    __shared__ float lds_in[64 * 100];
    __shared__ float lds_w[64 * 100];
    __shared__ float lds_z[64 * 68];
    const int tid = threadIdx.x;
    const int m0 = blockIdx.x * 64;
    const int c0 = (tid & 15) * 4, r0 = (tid >> 4) * 4;

    float acc[4][4];
    #pragma unroll
    for (int i = 0; i < 4; i++)
        #pragma unroll
        for (int j = 0; j < 4; j++) acc[i][j] = 0.f;

    #pragma unroll 1
    for (int q = 0; q < 5; q++) {
        const float* src = (q == 0) ? h : (q == 1) ? f1 : (q == 2) ? f2 : (q == 3) ? b1 : b2;
        {   // load input tile 64x64 fp32 ([m][64] rows)
            int row = tid >> 2, cc = (tid & 3) * 16;
            const float* sp = src + (size_t)(m0 + row) * HH + cc;
            float4 v0 = *(const float4*)(sp + 0);
            float4 v1 = *(const float4*)(sp + 4);
            float4 v2 = *(const float4*)(sp + 8);
            float4 v3 = *(const float4*)(sp + 12);
            *(float4*)&lds_in[row * 100 + cc + 0]  = v0;
            *(float4*)&lds_in[row * 100 + cc + 4]  = v1;
            *(float4*)&lds_in[row * 100 + cc + 8]  = v2;
            *(float4*)&lds_in[row * 100 + cc + 12] = v3;
        }
        {   // load filtW chunk rows q*64..
            int k = tid >> 2, cc = (tid & 3) * 16;
            const float* wp = filtW + (size_t)(q * 64 + k) * HH + cc;
            float4 v0 = *(const float4*)(wp + 0);
            float4 v1 = *(const float4*)(wp + 4);
            float4 v2 = *(const float4*)(wp + 8);
            float4 v3 = *(const float4*)(wp + 12);
            *(float4*)&lds_w[k * 100 + cc + 0]  = v0;
            *(float4*)&lds_w[k * 100 + cc + 4]  = v1;
            *(float4*)&lds_w[k * 100 + cc + 8]  = v2;
            *(float4*)&lds_w[k * 100 + cc + 12] = v3;
        }
        __syncthreads();
        #pragma unroll 4
        for (int k4 = 0; k4 < 64; k4 += 4) {
            float4 iv[4];
            #pragma unroll
            for (int i = 0; i < 4; i++)
                iv[i] = *(const float4*)&lds_in[(r0 + i) * 100 + k4];
            #pragma unroll
            for (int kk = 0; kk < 4; kk++) {
                const float4 wv = *(const float4*)&lds_w[(k4 + kk) * 100 + c0];
                #pragma unroll
                for (int i = 0; i < 4; i++) {
                    float a_ = f4c(iv[i], kk);
                    FMA4(acc[i], wv, a_);
                }
            }
        }
        __syncthreads();
    }
    {
        float fb[4];
        #pragma unroll
        for (int j = 0; j < 4; j++) fb[j] = filtb[c0 + j];
        #pragma unroll
        for (int i = 0; i < 4; i++)
            *(float4*)&lds_z[(r0 + i) * 68 + c0] =
                make_float4(acc[i][0] + fb[0], acc[i][1] + fb[1],
                            acc[i][2] + fb[2], acc[i][3] + fb[3]);
    }
    {   // load decW [64][96]
        int k = tid >> 2, cc = (tid & 3) * 24;
        const float* wp = decW + k * 96 + cc;
        float* dstp = &lds_w[k * 100 + cc];
        #pragma unroll
        for (int u = 0; u < 6; u++) {
            float4 v = *(const float4*)(wp + u * 4);
            *(float4*)(dstp + u * 4) = v;
        }
    }
    __syncthreads();

    const int c0b = (tid & 15) * 6;
    float acc2[4][6];
    #pragma unroll
    for (int i = 0; i < 4; i++)
        #pragma unroll
        for (int j = 0; j < 6; j++) acc2[i][j] = 0.f;
    #pragma unroll 4
    for (int k4 = 0; k4 < 64; k4 += 4) {
        float4 zv[4];
        #pragma unroll
        for (int i = 0; i < 4; i++)
            zv[i] = *(const float4*)&lds_z[(r0 + i) * 68 + k4];
        #pragma unroll
        for (int kk = 0; kk < 4; kk++) {
            float2 wa = *(const float2*)&lds_w[(k4 + kk) * 100 + c0b];
            float2 wb = *(const float2*)&lds_w[(k4 + kk) * 100 + c0b + 2];
            float2 wc = *(const float2*)&lds_w[(k4 + kk) * 100 + c0b + 4];
            #pragma unroll
            for (int i = 0; i < 4; i++) {
                float zz = f4c(zv[i], kk);
                acc2[i][0] = fmaf(zz, wa.x, acc2[i][0]);
                acc2[i][1] = fmaf(zz, wa.y, acc2[i][1]);
                acc2[i][2] = fmaf(zz, wb.x, acc2[i][2]);
                acc2[i][3] = fmaf(zz, wb.y, acc2[i][3]);
                acc2[i][4] = fmaf(zz, wc.x, acc2[i][4]);
                acc2[i][5] = fmaf(zz, wc.y, acc2[i][5]);
            }
        }
    }
    {
        float db[6];
        #pragma unroll
        for (int j = 0; j < 6; j++) db[j] = decb[c0b + j];
        #pragma unroll
        for (int i = 0; i < 4; i++)
            #pragma unroll
            for (int j = 0; j < 6; j++)
                lds_in[(r0 + i) * 100 + c0b + j] = acc2[i][j] + db[j];
    }
    __syncthreads();
    #pragma unroll 1
    for (int hor = 0; hor < HORZ; hor++) {
        int nl = tid >> 2, fp = tid & 3;
        int m = m0 + nl;
        int b = m / NN; int n = m - b * NN;
        float v0 = lds_in[nl * 100 + hor * 8 + 2 * fp];
        float v1 = lds_in[nl * 100 + hor * 8 + 2 * fp + 1];
        *(float2*)&out[(((size_t)b * HORZ + hor) * NN + n) * FF + 2 * fp] =
            make_float2(v0, v1);
    }
}

extern "C" void kernel_launch(void* const* d_in, const int* in_sizes, int n_in,
                              void* d_out, int out_size, void* d_ws, size_t ws_size,
                              hipStream_t stream) {
    (void)in_sizes; (void)n_in; (void)out_size; (void)ws_size;
    const float* x     = (const float*)d_in[0];
    const int*   ei    = (const int*)d_in[1];
    const float* ew    = (const float*)d_in[2];
    const float* encW  = (const float*)d_in[3];
    const float* encb  = (const float*)d_in[4];
    const float* emb   = (const float*)d_in[5];
    const float* wih   = (const float*)d_in[6];
    const float* whh   = (const float*)d_in[7];
    const float* bih   = (const float*)d_in[8];
    const float* bhh   = (const float*)d_in[9];
    const float* filtW = (const float*)d_in[10];
    const float* filtb = (const float*)d_in[11];
    const float* decW  = (const float*)d_in[12];
    const float* decb  = (const float*)d_in[13];
    float* out = (float*)d_out;

    float* ws = (float*)d_ws;
    float* h    = ws + OFF_H;
    float* f1   = ws + OFF_F1;
    float* f2   = ws + OFF_F2;
    float* b1   = ws + OFF_B1;
    float* b2   = ws + OFF_B2;
    float* bias = ws + OFF_BIAS;
    float* W1   = ws + OFF_W1;
    float* degf = ws + OFF_DEGF;
    float* degb = ws + OFF_DEGB;
    int* cntf = (int*)(ws + OFF_CNTF);
    int* cntb = (int*)(ws + OFF_CNTB);
    int* ptrf = (int*)(ws + OFF_PTRF);
    int* ptrb = (int*)(ws + OFF_PTRB);
    int* epkf = (int*)(ws + OFF_EPKF);
    int* epkb = (int*)(ws + OFF_EPKB);
    int* flag = (int*)(ws + OFF_FLAG);

    flag_k<<<1, 64, 0, stream>>>(ei, flag);
    zero_k<<<(40000 + 255) / 256, 256, 0, stream>>>(degf, 40000);
    csr_count_k<<<EE / 256, 256, 0, stream>>>(ei, ew, flag, cntf, cntb, degf, degb);
    scan_k<<<2, 256, 0, stream>>>(cntf, cntb, ptrf, ptrb);
    csr_fill_k<<<EE / 256, 256, 0, stream>>>(ei, ew, flag, degf, degb, ptrf, ptrb,
                                             cntf, cntb, epkf, epkb);
    w1_k<<<(FF * GG + 255) / 256, 256, 0, stream>>>(encW, wih, W1);
    biasA_k<<<(NN + 63) / 64, 256, 0, stream>>>(emb, encb, wih, bih, bhh, bias);
    gru_k<<<MM / 64, 256, 0, stream>>>(x, bias, W1, whh, bhh, h);
    {
        dim3 g(NN / 4, BB, 2);
        prop_k<<<g, 256, 0, stream>>>(h,  f1, ptrf, (const long long*)epkf,
                                      h,  b1, ptrb, (const long long*)epkb);
        prop_k<<<g, 256, 0, stream>>>(f1, f2, ptrf, (const long long*)epkf,
                                      b1, b2, ptrb, (const long long*)epkb);
    }
    filtdec_k<<<MM / 64, 256, 0, stream>>>(h, f1, f2, b1, b2,
                                           filtW, filtb, decW, decb, out);
}

// Round 8
// 654.837 us; speedup vs baseline: 1.8528x; 1.3255x over previous
//
#include <hip/hip_runtime.h>

typedef unsigned short ushort_t;

#define NN 10000
#define BB 8
#define TT 12
#define FF 8
#define HH 64
#define GG 192   // 3H
#define HORZ 12
#define EE 320000
#define MM (BB*NN) // 80000

// ---- ws layout (float words) ----
#define OFF_H    0u
#define OFF_F1   5120000u
#define OFF_F2   10240000u
#define OFF_B1   15360000u
#define OFF_B2   20480000u
#define OFF_BIAS 25600000u
#define OFF_W1   27520000u
#define OFF_DEGF 27521536u
#define OFF_DEGB 27531536u
#define OFF_CNTF 27541536u
#define OFF_CNTB 27551536u
#define OFF_PTRF 27561536u
#define OFF_PTRB 27571537u
#define OFF_EPKF 27581538u   // packed (idx, w) int2 per edge, fwd (640000 words)
#define OFF_EPKB 28221538u   // packed (idx, w) int2 per edge, bwd (640000 words)
#define OFF_FLAG 28861538u

typedef __attribute__((ext_vector_type(8))) short short8;
typedef __attribute__((ext_vector_type(4))) float f4v;

union I4S8 { int4 i; short8 s; };

__device__ __forceinline__ f4v mfma16(int4 a, int4 b, f4v c) {
    I4S8 ua, ub; ua.i = a; ub.i = b;
    return __builtin_amdgcn_mfma_f32_16x16x32_bf16(ua.s, ub.s, c, 0, 0, 0);
}

__device__ __forceinline__ unsigned f2bf_u(float f) {
    union { float f; unsigned u; } v; v.f = f;
    unsigned x = v.u;
    x += 0x7FFFu + ((x >> 16) & 1u);
    return x >> 16;
}
// pack 8 fp32 -> bf16 (round-to-nearest) fragment
__device__ __forceinline__ int4 hi8(const float* f) {
    unsigned hb[8];
    #pragma unroll
    for (int i = 0; i < 8; i++) hb[i] = f2bf_u(f[i]);
    return make_int4((int)(hb[0]|(hb[1]<<16)), (int)(hb[2]|(hb[3]<<16)),
                     (int)(hb[4]|(hb[5]<<16)), (int)(hb[6]|(hb[7]<<16)));
}

__device__ __forceinline__ float f4c(const float4& v, int kk) {
    switch (kk) { case 0: return v.x; case 1: return v.y; case 2: return v.z; default: return v.w; }
}
#define FMA4(ACC, W, S) \
    ACC[0] = fmaf(S, W.x, ACC[0]); \
    ACC[1] = fmaf(S, W.y, ACC[1]); \
    ACC[2] = fmaf(S, W.z, ACC[2]); \
    ACC[3] = fmaf(S, W.w, ACC[3]);

// ---------------- utility ----------------
__global__ void zero_k(float* p, int n) {
    int i = blockIdx.x * 256 + threadIdx.x;
    if (i < n) p[i] = 0.f;
}

__global__ void flag_k(const int* __restrict__ ei, int* flag) {
    if (threadIdx.x == 0 && blockIdx.x == 0) {
        int o = ei[1] | ei[3] | ei[5] | ei[7] | ei[9] | ei[11] | ei[13];
        flag[0] = (o == 0) ? 1 : 0;
    }
}

__device__ __forceinline__ void load_edge(const int* __restrict__ ei, int isI64,
                                          int e, int& s, int& t) {
    if (isI64) {
        const long long* p = (const long long*)ei;
        s = (int)p[e]; t = (int)p[EE + e];
    } else {
        s = ei[e]; t = ei[EE + e];
    }
}

// ---------------- CSR build ----------------
__global__ void csr_count_k(const int* __restrict__ ei, const float* __restrict__ ew,
                            const int* __restrict__ flag,
                            int* cnt_f, int* cnt_b, float* deg_f, float* deg_b) {
    int e = blockIdx.x * 256 + threadIdx.x;
    if (e >= EE) return;
    int isI64 = flag[0];
    int s, t; load_edge(ei, isI64, e, s, t);
    if ((unsigned)s >= NN || (unsigned)t >= NN) return;
    float w = ew[e];
    atomicAdd(&cnt_f[t], 1); atomicAdd(&deg_f[t], w);
    atomicAdd(&cnt_b[s], 1); atomicAdd(&deg_b[s], w);
}

__global__ void scan_k(int* cnt_f, int* cnt_b, int* ptr_f, int* ptr_b) {
    int* cnt = blockIdx.x ? cnt_b : cnt_f;
    int* ptr = blockIdx.x ? ptr_b : ptr_f;
    __shared__ int part[256];
    int tid = threadIdx.x;
    const int CH = (NN + 255) / 256;
    int lo = tid * CH, hi = lo + CH; if (hi > NN) hi = NN; if (lo > NN) lo = NN;
    int s = 0;
    for (int i = lo; i < hi; i++) s += cnt[i];
    part[tid] = s;
    __syncthreads();
    if (tid == 0) {
        int run = 0;
        for (int i = 0; i < 256; i++) { int v = part[i]; part[i] = run; run += v; }
        ptr[NN] = run;
    }
    __syncthreads();
    int run = part[tid];
    for (int i = lo; i < hi; i++) { ptr[i] = run; run += cnt[i]; cnt[i] = 0; }
}

__global__ void csr_fill_k(const int* __restrict__ ei, const float* __restrict__ ew,
                           const int* __restrict__ flag,
                           const float* __restrict__ deg_f, const float* __restrict__ deg_b,
                           const int* __restrict__ ptr_f, const int* __restrict__ ptr_b,
                           int* cnt_f, int* cnt_b,
                           int* epk_f, int* epk_b) {
    int e = blockIdx.x * 256 + threadIdx.x;
    if (e >= EE) return;
    int isI64 = flag[0];
    int s, t; load_edge(ei, isI64, e, s, t);
    if ((unsigned)s >= NN || (unsigned)t >= NN) return;
    float w = ew[e];
    float df = deg_f[t];
    float nwf = w / ((df == 0.f) ? 1.f : df);
    int p = ptr_f[t] + atomicAdd(&cnt_f[t], 1);
    epk_f[2 * p] = s; epk_f[2 * p + 1] = __float_as_int(nwf);
    float db = deg_b[s];
    float nwb = w / ((db == 0.f) ? 1.f : db);
    int p2 = ptr_b[s] + atomicAdd(&cnt_b[s], 1);
    epk_b[2 * p2] = t; epk_b[2 * p2 + 1] = __float_as_int(nwb);
}

// ---------------- precompute W1 = enc_W @ Wih^T  [8][192] ----------------
__global__ void w1_k(const float* __restrict__ encW, const float* __restrict__ wih,
                     float* __restrict__ W1) {
    int id = blockIdx.x * 256 + threadIdx.x;
    if (id >= FF * GG) return;
    int f = id / GG, g = id - f * GG;
    float acc = 0.f;
    for (int hh = 0; hh < HH; hh++)
        acc = fmaf(encW[f * HH + hh], wih[g * HH + hh], acc);
    W1[id] = acc;
}

// ---- biasA[n][g] = bih[g] + (g<128? bhh[g]:0) + sum_h (enc_b+emb[n])*Wih[g][h] ----
__global__ __launch_bounds__(256, 2)
void biasA_k(const float* __restrict__ emb, const float* __restrict__ encb,
             const float* __restrict__ wih, const float* __restrict__ bih,
             const float* __restrict__ bhh, float* __restrict__ biasA) {
    __shared__ float wl[HH * GG];   // wl[h][g] = Wih[g][h]
    __shared__ float et[64 * 68];   // enc_b + emb tile
    const int tid = threadIdx.x;
    const int n0 = blockIdx.x * 64;
    for (int idx = tid * 4; idx < GG * HH; idx += 1024) {
        float4 v = *(const float4*)&wih[idx];
        int g = idx >> 6, hh = idx & 63;
        wl[hh * GG + g] = v.x;
        wl[(hh + 1) * GG + g] = v.y;
        wl[(hh + 2) * GG + g] = v.z;
        wl[(hh + 3) * GG + g] = v.w;
    }
    {
        int row = tid >> 2, cc = (tid & 3) * 16;
        int n = n0 + row;
        #pragma unroll
        for (int u = 0; u < 4; u++) {
            float4 e4 = (n < NN) ? *(const float4*)&emb[(size_t)n * HH + cc + u * 4]
                                 : make_float4(0.f, 0.f, 0.f, 0.f);
            float4 b4 = *(const float4*)&encb[cc + u * 4];
            *(float4*)&et[row * 68 + cc + u * 4] =
                make_float4(e4.x + b4.x, e4.y + b4.y, e4.z + b4.z, e4.w + b4.w);
        }
    }
    __syncthreads();
    const int r0 = (tid >> 4) * 4;
    #pragma unroll 1
    for (int p = 0; p < 3; p++) {
        const int c0 = p * 64 + (tid & 15) * 4;
        float acc[4][4];
        float4 bi = *(const float4*)&bih[c0];
        float4 bh = (c0 < 128) ? *(const float4*)&bhh[c0] : make_float4(0.f, 0.f, 0.f, 0.f);
        #pragma unroll
        for (int i = 0; i < 4; i++) {
            acc[i][0] = bi.x + bh.x; acc[i][1] = bi.y + bh.y;
            acc[i][2] = bi.z + bh.z; acc[i][3] = bi.w + bh.w;
        }
        #pragma unroll 4
        for (int k4 = 0; k4 < 64; k4 += 4) {
            float4 hv[4];
            #pragma unroll
            for (int i = 0; i < 4; i++)
                hv[i] = *(const float4*)&et[(r0 + i) * 68 + k4];
            #pragma unroll
            for (int kk = 0; kk < 4; kk++) {
                const float4 wv = *(const float4*)&wl[(k4 + kk) * GG + c0];
                #pragma unroll
                for (int i = 0; i < 4; i++) {
                    float a_ = f4c(hv[i], kk);
                    FMA4(acc[i], wv, a_);
                }
            }
        }
        #pragma unroll
        for (int i = 0; i < 4; i++) {
            int n = n0 + r0 + i;
            if (n < NN)
                *(float4*)&biasA[(size_t)n * GG + c0] =
                    make_float4(acc[i][0], acc[i][1], acc[i][2], acc[i][3]);
        }
    }
}

// ---------------- MFMA GRU: all 12 steps, no barriers in loop ----------------
// h scratch bf16 in A-fragment layout; reads via __builtin_memcpy (alias-safe —
// ushort stores + typed 64b loads were reordered by TBAA in the r7 NaN bug).
__global__ __launch_bounds__(256, 2)
void gru_k(const float* __restrict__ x, const float* __restrict__ biasA,
           const float* __restrict__ W1, const float* __restrict__ whh,
           const float* __restrict__ bhh, float* __restrict__ h_out) {
    __shared__ int lds_B[24 * 64 * 4];                     // Whh B-frags (24 KB)
    __shared__ __align__(16) ushort_t lds_hb[4][16 * 68];  // per-wave h bf16

    const int tid = threadIdx.x;
    const int wave = tid >> 6, ln = tid & 63;
    const int quad = ln >> 4, lx = ln & 15;
    const int m0 = blockIdx.x * 64;
    ushort_t* hbw = (ushort_t*)lds_hb[wave];

    // stage Whh B-frags: fid=(c*2+q): B[k = q*32 + (ln>>4)*8 + j][g = c*16 + (ln&15)]
    #pragma unroll
    for (int it = 0; it < 6; it++) {
        int slot = tid + it * 256;
        int fid = slot >> 6, l2 = slot & 63;
        int c = fid >> 1, q = fid & 1;
        int g = c * 16 + (l2 & 15);
        int k0 = q * 32 + ((l2 >> 4) & 3) * 8;
        const float* wp = whh + (size_t)g * HH + k0;
        float4 v0 = *(const float4*)wp;
        float4 v1 = *(const float4*)(wp + 4);
        float fv[8] = {v0.x, v0.y, v0.z, v0.w, v1.x, v1.y, v1.z, v1.w};
        *(int4*)&lds_B[slot * 4] = hi8(fv);
    }

    // W1 B-frags in registers (K=32 padded; only k<8 real -> lanes 0-15)
    int4 w1f[12];
    #pragma unroll
    for (int j = 0; j < 12; j++) w1f[j] = make_int4(0, 0, 0, 0);
    if (ln < 16) {
        #pragma unroll
        for (int j = 0; j < 12; j++) {
            int col = j * 16 + ln;
            float fv[8];
            #pragma unroll
            for (int k = 0; k < 8; k++) fv[k] = W1[k * GG + col];
            w1f[j] = hi8(fv);
        }
    }

    // per-lane biases (C-layout positions)
    f4v bR[4], bZ[4], bNx[4];
    float bHn[4];
    int rown[4];
    #pragma unroll
    for (int reg = 0; reg < 4; reg++) {
        int m = m0 + wave * 16 + quad * 4 + reg;
        int b = m / NN; rown[reg] = m - b * NN;
    }
    #pragma unroll
    for (int j = 0; j < 4; j++) {
        int c = j * 16 + lx;
        #pragma unroll
        for (int reg = 0; reg < 4; reg++) {
            const float* bp = biasA + (size_t)rown[reg] * GG;
            bR[j][reg]  = bp[c];
            bZ[j][reg]  = bp[64 + c];
            bNx[j][reg] = bp[128 + c];
        }
        bHn[j] = bhh[128 + c];
    }

    // x pointer + first-step preload (rows owned: m0 + wave*16 + ln, lanes 0-15)
    const float* xp = x;
    float4 xc0 = make_float4(0.f,0.f,0.f,0.f), xc1 = xc0;
    if (ln < 16) {
        int m = m0 + wave * 16 + ln;
        int b = m / NN; int n = m - b * NN;
        xp = x + ((size_t)(b * TT) * NN + n) * FF;
        xc0 = *(const float4*)xp;
        xc1 = *(const float4*)(xp + 4);
    }

    __syncthreads();   // lds_B ready (only barrier)

    f4v hp[4];
    #pragma unroll
    for (int j = 0; j < 4; j++) hp[j] = (f4v){0.f, 0.f, 0.f, 0.f};

    #pragma unroll 1
    for (int t = 0; t < TT; t++) {
        // pack current x A-frag (hi only)
        int4 axh = make_int4(0, 0, 0, 0);
        {
            float fv[8] = {xc0.x, xc0.y, xc0.z, xc0.w, xc1.x, xc1.y, xc1.z, xc1.w};
            if (ln < 16) axh = hi8(fv);
        }
        // prefetch next-step x (in flight during MFMAs + gates)
        if (t < TT - 1 && ln < 16) {
            const float* xq = xp + (size_t)(t + 1) * (NN * FF);
            xc0 = *(const float4*)xq;
            xc1 = *(const float4*)(xq + 4);
        }

        // h A-frags from bf16 LDS (A-layout: row=lx, chans q*32+quad*8..+7)
        int4 ahf[2];
        if (t) {
            const ushort_t* h0 = hbw + lx * 68 + quad * 8;
            long long a00, a01, a10, a11;
            __builtin_memcpy(&a00, h0, 8);
            __builtin_memcpy(&a01, h0 + 4, 8);
            __builtin_memcpy(&a10, h0 + 32, 8);
            __builtin_memcpy(&a11, h0 + 36, 8);
            ahf[0] = make_int4((int)a00, (int)(a00 >> 32), (int)a01, (int)(a01 >> 32));
            ahf[1] = make_int4((int)a10, (int)(a10 >> 32), (int)a11, (int)(a11 >> 32));
        }

        f4v accR[4], accZ[4], accNx[4], accNh[4];
        #pragma unroll
        for (int j = 0; j < 4; j++) {
            accR[j]  = mfma16(axh, w1f[j],     bR[j]);
            accZ[j]  = mfma16(axh, w1f[j + 4], bZ[j]);
            accNx[j] = mfma16(axh, w1f[j + 8], bNx[j]);
            accNh[j] = (f4v){bHn[j], bHn[j], bHn[j], bHn[j]};
        }
        if (t) {
            #pragma unroll
            for (int j = 0; j < 4; j++) {
                #pragma unroll
                for (int q = 0; q < 2; q++) {
                    int4 bRf = *(const int4*)&lds_B[((j * 2 + q) * 64 + ln) * 4];
                    int4 bZf = *(const int4*)&lds_B[(((j + 4) * 2 + q) * 64 + ln) * 4];
                    int4 bNf = *(const int4*)&lds_B[(((j + 8) * 2 + q) * 64 + ln) * 4];
                    accR[j]  = mfma16(ahf[q], bRf, accR[j]);
                    accZ[j]  = mfma16(ahf[q], bZf, accZ[j]);
                    accNh[j] = mfma16(ahf[q], bNf, accNh[j]);
                }
            }
        }

        // gates + bf16 h write (per-wave private LDS; same-wave DS in-order)
        #pragma unroll
        for (int j = 0; j < 4; j++) {
            #pragma unroll
            for (int reg = 0; reg < 4; reg++) {
                float rr = 1.f / (1.f + __expf(-accR[j][reg]));
                float zz = 1.f / (1.f + __expf(-accZ[j][reg]));
                float pre = fmaf(rr, accNh[j][reg], accNx[j][reg]);
                pre = fminf(fmaxf(pre, -30.f), 30.f);
                float e2 = __expf(pre + pre);
                float nn = (e2 - 1.f) / (e2 + 1.f);
                float hv = (1.f - zz) * nn + zz * hp[j][reg];
                hp[j][reg] = hv;
                hbw[(quad * 4 + reg) * 68 + j * 16 + lx] = (ushort_t)f2bf_u(hv);
            }
        }
    }

    // epilogue: h_out[m][64] straight from registers (C-layout, 64B segments)
    #pragma unroll
    for (int j = 0; j < 4; j++) {
        #pragma unroll
        for (int reg = 0; reg < 4; reg++) {
            int m = m0 + wave * 16 + quad * 4 + reg;
            h_out[(size_t)m * HH + j * 16 + lx] = hp[j][reg];
        }
    }
}

// ---------------- diffusion: batch-chunked, LDS-staged edge broadcast ----------------
__global__ __launch_bounds__(256)
void prop_k(const float* __restrict__ srcF, float* __restrict__ dstF,
            const int* __restrict__ ptrF, const long long* __restrict__ epkF,
            const float* __restrict__ srcB, float* __restrict__ dstB,
            const int* __restrict__ ptrB, const long long* __restrict__ epkB) {
    __shared__ long long erec[4][64];
    const int wv = threadIdx.x >> 6;
    const int ln = threadIdx.x & 63;
    const int node = blockIdx.x * 4 + wv;
    const int b = blockIdx.y;
    const float* src; float* dst; const int* ptr; const long long* ep;
    if (blockIdx.z == 0) { src = srcF; dst = dstF; ptr = ptrF; ep = epkF; }
    else                 { src = srcB; dst = dstB; ptr = ptrB; ep = epkB; }
    const float* sb = src + (size_t)b * (NN * HH) + ln;
    const int e0 = ptr[node], e1 = ptr[node + 1];
    float ac0 = 0.f, ac1 = 0.f, ac2 = 0.f, ac3 = 0.f;
    for (int base = e0; base < e1; base += 64) {
        int cnt = e1 - base; if (cnt > 64) cnt = 64;
        if (ln < cnt) erec[wv][ln] = ep[base + ln];   // cached, coalesced 512B
        int j = 0;
        for (; j + 4 <= cnt; j += 4) {
            long long p0 = erec[wv][j + 0];
            long long p1 = erec[wv][j + 1];
            long long p2 = erec[wv][j + 2];
            long long p3 = erec[wv][j + 3];
            float g0 = sb[(size_t)(int)p0 * HH];
            float g1 = sb[(size_t)(int)p1 * HH];
            float g2 = sb[(size_t)(int)p2 * HH];
            float g3 = sb[(size_t)(int)p3 * HH];
            ac0 = fmaf(g0, __int_as_float((int)(p0 >> 32)), ac0);
            ac1 = fmaf(g1, __int_as_float((int)(p1 >> 32)), ac1);
            ac2 = fmaf(g2, __int_as_float((int)(p2 >> 32)), ac2);
            ac3 = fmaf(g3, __int_as_float((int)(p3 >> 32)), ac3);
        }
        for (; j < cnt; j++) {
            long long p0 = erec[wv][j];
            ac0 = fmaf(sb[(size_t)(int)p0 * HH], __int_as_float((int)(p0 >> 32)), ac0);
        }
    }
    __builtin_nontemporal_store((ac0 + ac1) + (ac2 + ac3),
                                &dst[((size_t)b * NN + node) * HH + ln]);
}

// ---------------- fused filter (K=320) + decoder (K=64) ----------------
__global__ __launch_bounds__(256, 2)
void filtdec_k(const float* __restrict__ h, const float* __restrict__ f1,
               const float* __restrict__ f2, const float* __restrict__ b1,
               const float* __restrict__ b2,
               const float* __restrict__ filtW, const float* __restrict__ filtb,
               const float* __restrict__ decW, const float* __restrict__ decb,
               float* __restrict__ out) {
    __shared__ float lds_in[64 * 100];
    __shared__ float lds_w[64 * 100];
    __shared__ float lds_z[64 * 68];
    const int tid = threadIdx.x;
    const int m0 = blockIdx.x * 64;
    const int c0 = (tid & 15) * 4, r0 = (tid >> 4) * 4;

    float acc[4][4];
    #pragma unroll
    for (int i = 0; i < 4; i++)
        #pragma unroll
        for (int j = 0; j < 4; j++) acc[i][j] = 0.f;

    #pragma unroll 1
    for (int q = 0; q < 5; q++) {
        const float* src = (q == 0) ? h : (q == 1) ? f1 : (q == 2) ? f2 : (q == 3) ? b1 : b2;
        {   // load input tile 64x64 fp32 ([m][64] rows)
            int row = tid >> 2, cc = (tid & 3) * 16;
            const float* sp = src + (size_t)(m0 + row) * HH + cc;
            float4 v0 = *(const float4*)(sp + 0);
            float4 v1 = *(const float4*)(sp + 4);
            float4 v2 = *(const float4*)(sp + 8);
            float4 v3 = *(const float4*)(sp + 12);
            *(float4*)&lds_in[row * 100 + cc + 0]  = v0;
            *(float4*)&lds_in[row * 100 + cc + 4]  = v1;
            *(float4*)&lds_in[row * 100 + cc + 8]  = v2;
            *(float4*)&lds_in[row * 100 + cc + 12] = v3;
        }
        {   // load filtW chunk rows q*64..
            int k = tid >> 2, cc = (tid & 3) * 16;
            const float* wp = filtW + (size_t)(q * 64 + k) * HH + cc;
            float4 v0 = *(const float4*)(wp + 0);
            float4 v1 = *(const float4*)(wp + 4);
            float4 v2 = *(const float4*)(wp + 8);
            float4 v3 = *(const float4*)(wp + 12);
            *(float4*)&lds_w[k * 100 + cc + 0]  = v0;
            *(float4*)&lds_w[k * 100 + cc + 4]  = v1;
            *(float4*)&lds_w[k * 100 + cc + 8]  = v2;
            *(float4*)&lds_w[k * 100 + cc + 12] = v3;
        }
        __syncthreads();
        #pragma unroll 4
        for (int k4 = 0; k4 < 64; k4 += 4) {
            float4 iv[4];
            #pragma unroll
            for (int i = 0; i < 4; i++)
                iv[i] = *(const float4*)&lds_in[(r0 + i) * 100 + k4];
            #pragma unroll
            for (int kk = 0; kk < 4; kk++) {
                const float4 wv = *(const float4*)&lds_w[(k4 + kk) * 100 + c0];
                #pragma unroll
                for (int i = 0; i < 4; i++) {
                    float a_ = f4c(iv[i], kk);
                    FMA4(acc[i], wv, a_);
                }
            }
        }
        __syncthreads();
    }
    {
        float fb[4];
        #pragma unroll
        for (int j = 0; j < 4; j++) fb[j] = filtb[c0 + j];
        #pragma unroll
        for (int i = 0; i < 4; i++)
            *(float4*)&lds_z[(r0 + i) * 68 + c0] =
                make_float4(acc[i][0] + fb[0], acc[i][1] + fb[1],
                            acc[i][2] + fb[2], acc[i][3] + fb[3]);
    }
    {   // load decW [64][96]
        int k = tid >> 2, cc = (tid & 3) * 24;
        const float* wp = decW + k * 96 + cc;
        float* dstp = &lds_w[k * 100 + cc];
        #pragma unroll
        for (int u = 0; u < 6; u++) {
            float4 v = *(const float4*)(wp + u * 4);
            *(float4*)(dstp + u * 4) = v;
        }
    }
    __syncthreads();

    const int c0b = (tid & 15) * 6;
    float acc2[4][6];
    #pragma unroll
    for (int i = 0; i < 4; i++)
        #pragma unroll
        for (int j = 0; j < 6; j++) acc2[i][j] = 0.f;
    #pragma unroll 4
    for (int k4 = 0; k4 < 64; k4 += 4) {
        float4 zv[4];
        #pragma unroll
        for (int i = 0; i < 4; i++)
            zv[i] = *(const float4*)&lds_z[(r0 + i) * 68 + k4];
        #pragma unroll
        for (int kk = 0; kk < 4; kk++) {
            float2 wa = *(const float2*)&lds_w[(k4 + kk) * 100 + c0b];
            float2 wb = *(const float2*)&lds_w[(k4 + kk) * 100 + c0b + 2];
            float2 wc = *(const float2*)&lds_w[(k4 + kk) * 100 + c0b + 4];
            #pragma unroll
            for (int i = 0; i < 4; i++) {
                float zz = f4c(zv[i], kk);
                acc2[i][0] = fmaf(zz, wa.x, acc2[i][0]);
                acc2[i][1] = fmaf(zz, wa.y, acc2[i][1]);
                acc2[i][2] = fmaf(zz, wb.x, acc2[i][2]);
                acc2[i][3] = fmaf(zz, wb.y, acc2[i][3]);
                acc2[i][4] = fmaf(zz, wc.x, acc2[i][4]);
                acc2[i][5] = fmaf(zz, wc.y, acc2[i][5]);
            }
        }
    }
    {
        float db[6];
        #pragma unroll
        for (int j = 0; j < 6; j++) db[j] = decb[c0b + j];
        #pragma unroll
        for (int i = 0; i < 4; i++)
            #pragma unroll
            for (int j = 0; j < 6; j++)
                lds_in[(r0 + i) * 100 + c0b + j] = acc2[i][j] + db[j];
    }
    __syncthreads();
    #pragma unroll 1
    for (int hor = 0; hor < HORZ; hor++) {
        int nl = tid >> 2, fp = tid & 3;
        int m = m0 + nl;
        int b = m / NN; int n = m - b * NN;
        float v0 = lds_in[nl * 100 + hor * 8 + 2 * fp];
        float v1 = lds_in[nl * 100 + hor * 8 + 2 * fp + 1];
        *(float2*)&out[(((size_t)b * HORZ + hor) * NN + n) * FF + 2 * fp] =
            make_float2(v0, v1);
    }
}

extern "C" void kernel_launch(void* const* d_in, const int* in_sizes, int n_in,
                              void* d_out, int out_size, void* d_ws, size_t ws_size,
                              hipStream_t stream) {
    (void)in_sizes; (void)n_in; (void)out_size; (void)ws_size;
    const float* x     = (const float*)d_in[0];
    const int*   ei    = (const int*)d_in[1];
    const float* ew    = (const float*)d_in[2];
    const float* encW  = (const float*)d_in[3];
    const float* encb  = (const float*)d_in[4];
    const float* emb   = (const float*)d_in[5];
    const float* wih   = (const float*)d_in[6];
    const float* whh   = (const float*)d_in[7];
    const float* bih   = (const float*)d_in[8];
    const float* bhh   = (const float*)d_in[9];
    const float* filtW = (const float*)d_in[10];
    const float* filtb = (const float*)d_in[11];
    const float* decW  = (const float*)d_in[12];
    const float* decb  = (const float*)d_in[13];
    float* out = (float*)d_out;

    float* ws = (float*)d_ws;
    float* h    = ws + OFF_H;
    float* f1   = ws + OFF_F1;
    float* f2   = ws + OFF_F2;
    float* b1   = ws + OFF_B1;
    float* b2   = ws + OFF_B2;
    float* bias = ws + OFF_BIAS;
    float* W1   = ws + OFF_W1;
    float* degf = ws + OFF_DEGF;
    float* degb = ws + OFF_DEGB;
    int* cntf = (int*)(ws + OFF_CNTF);
    int* cntb = (int*)(ws + OFF_CNTB);
    int* ptrf = (int*)(ws + OFF_PTRF);
    int* ptrb = (int*)(ws + OFF_PTRB);
    int* epkf = (int*)(ws + OFF_EPKF);
    int* epkb = (int*)(ws + OFF_EPKB);
    int* flag = (int*)(ws + OFF_FLAG);

    flag_k<<<1, 64, 0, stream>>>(ei, flag);
    zero_k<<<(40000 + 255) / 256, 256, 0, stream>>>(degf, 40000);
    csr_count_k<<<EE / 256, 256, 0, stream>>>(ei, ew, flag, cntf, cntb, degf, degb);
    scan_k<<<2, 256, 0, stream>>>(cntf, cntb, ptrf, ptrb);
    csr_fill_k<<<EE / 256, 256, 0, stream>>>(ei, ew, flag, degf, degb, ptrf, ptrb,
                                             cntf, cntb, epkf, epkb);
    w1_k<<<(FF * GG + 255) / 256, 256, 0, stream>>>(encW, wih, W1);
    biasA_k<<<(NN + 63) / 64, 256, 0, stream>>>(emb, encb, wih, bih, bhh, bias);
    gru_k<<<MM / 64, 256, 0, stream>>>(x, bias, W1, whh, bhh, h);
    {
        dim3 g(NN / 4, BB, 2);
        prop_k<<<g, 256, 0, stream>>>(h,  f1, ptrf, (const long long*)epkf,
                                      h,  b1, ptrb, (const long long*)epkb);
        prop_k<<<g, 256, 0, stream>>>(f1, f2, ptrf, (const long long*)epkf,
                                      b1, b2, ptrb, (const long long*)epkb);
    }
    filtdec_k<<<MM / 64, 256, 0, stream>>>(h, f1, f2, b1, b2,
                                           filtW, filtb, decW, decb, out);
}